// Round 7
// baseline (502.634 us; speedup 1.0000x reference)
//
#include <hip/hip_runtime.h>

#define B 4
#define M 8192
#define NSTY 8192
#define KNB 8
#define F 288
#define NT (M + NSTY)   // 16384
#define BM (B * M)      // 32768
#define SEGL (M * F)    // 2359296 elements per convert segment

typedef __attribute__((ext_vector_type(8))) short short8;
typedef __attribute__((ext_vector_type(4))) float floatx4;
typedef __attribute__((ext_vector_type(2))) float floatx2;

__device__ __forceinline__ float u2f(unsigned int u) {
    union { unsigned int u; float f; } c; c.u = u; return c.f;
}
__device__ __forceinline__ unsigned short f2b(float x) {
    union { float f; unsigned int u; } c; c.f = x;
    unsigned int r = c.u + 0x7FFFu + ((c.u >> 16) & 1u);
    return (unsigned short)(r >> 16);
}
__device__ __forceinline__ floatx2 bpair(unsigned int p) {
    floatx2 r;
    r.x = u2f(p << 16);
    r.y = u2f(p & 0xFFFF0000u);
    return r;
}

// ---------------- merged prep: convert (16 elems/thread) | deg histogram | pack W ----------------
#define PREP_CVT   4608    // 8 segments x 576 blocks; 4096 elems/block
#define PREP_DEG   1024
#define PREP_PKW   648
__global__ void prep_kernel(const int* __restrict__ idx_k1, const int* __restrict__ idx_k2,
                            int* __restrict__ deg,
                            const float* __restrict__ fc, const float* __restrict__ fs,
                            unsigned short* __restrict__ fb,
                            const float* __restrict__ W1, const float* __restrict__ W2,
                            unsigned short* __restrict__ Wp1, unsigned short* __restrict__ Wp2) {
    int blk = blockIdx.x;
    if (blk < PREP_CVT) {
        int seg = blk / 576;
        int bis = blk - seg * 576;
        int b = seg >> 1, sty = seg & 1;
        unsigned int e = (unsigned int)bis * 4096 + threadIdx.x * 16;
        const float* src = (sty ? fs : fc) + (size_t)b * SEGL + e;
        float4 x0 = *(const float4*)src;
        float4 x1 = *(const float4*)(src + 4);
        float4 x2 = *(const float4*)(src + 8);
        float4 x3 = *(const float4*)(src + 12);
        uint4 o0, o1;
        o0.x = (unsigned int)f2b(x0.x) | ((unsigned int)f2b(x0.y) << 16);
        o0.y = (unsigned int)f2b(x0.z) | ((unsigned int)f2b(x0.w) << 16);
        o0.z = (unsigned int)f2b(x1.x) | ((unsigned int)f2b(x1.y) << 16);
        o0.w = (unsigned int)f2b(x1.z) | ((unsigned int)f2b(x1.w) << 16);
        o1.x = (unsigned int)f2b(x2.x) | ((unsigned int)f2b(x2.y) << 16);
        o1.y = (unsigned int)f2b(x2.z) | ((unsigned int)f2b(x2.w) << 16);
        o1.z = (unsigned int)f2b(x3.x) | ((unsigned int)f2b(x3.y) << 16);
        o1.w = (unsigned int)f2b(x3.z) | ((unsigned int)f2b(x3.w) << 16);
        unsigned short* d = fb + (size_t)b * 2 * SEGL + (size_t)sty * SEGL + e;
        *(uint4*)d = o0;
        *(uint4*)(d + 8) = o1;
    } else if (blk < PREP_CVT + PREP_DEG) {
        int t = (blk - PREP_CVT) * 256 + threadIdx.x;
        int b = t >> 16;                                 // M*KNB == 65536
        atomicAdd(&deg[b * NT + idx_k2[t]], 1);
        atomicAdd(&deg[b * NT + M + idx_k1[t]], 1);
    } else {
        int t = (blk - PREP_CVT - PREP_DEG) * 256 + threadIdx.x;
        if (t >= 2 * F * F) return;
        int half = t >= F * F;
        int tt = t - half * F * F;
        int k = tt / F, n = tt - k * F;
        const float* W = half ? W2 : W1;
        unsigned short* Wp = half ? Wp2 : Wp1;
        Wp[((size_t)(k >> 3) * F + n) * 8 + (k & 7)] = f2b(W[tt]);
    }
}

// ---------------- fused gather + MFMA GEMM (sA-only LDS, barrier-free K-loop) ----------------
// Phase A: 4 waves gather 16 rows each (round-5 structure) into sA (bf16).
// Phase B: 2x2 wave grid, B-fragments read DIRECTLY from global Wp (L2-hot, 166 KB).
// LAYER 1: src=featb[B][NT][F], 16 nbrs, out=h1b bf16 (+relu). LAYER 2: src=h1b[B][M][F],
// 8 nbrs + style const, out=fp32.
template<int LAYER>
__global__ __launch_bounds__(256, 4) void fused_kernel(
        const unsigned short* __restrict__ src_tbl,
        const int* __restrict__ idx_k1, const int* __restrict__ idx_k2,
        const int* __restrict__ deg, const float* __restrict__ b1,
        const unsigned short* __restrict__ Wp, const float* __restrict__ bias,
        void* __restrict__ Cout) {
    __shared__ __align__(16) unsigned short sA[64 * F];   // 36864 B
    const int NK = (LAYER == 1) ? 16 : 8;
    int tid = threadIdx.x, wid = tid >> 6, lane = tid & 63;
    int blk = blockIdx.x;
    int rx = blk & 7;
    int b = rx >> 1;                           // batch (2 XCDs per batch)
    int sub = (blk >> 3) * 2 + (rx & 1);       // [0, 128) 64-row tile within batch
    int row0 = b * M + sub * 64;               // global dst row base

    // ---- phase A: gather 64 rows into sA; wave wid does local rows [wid*16, wid*16+16) ----
    int i4 = lane >> 4, e = lane & 15;
    float bb[8];
    if (LAYER == 2 && lane < 36) {
        float4 t0 = *(const float4*)(b1 + 8 * lane);
        float4 t1 = *(const float4*)(b1 + 8 * lane + 4);
        bb[0]=fmaxf(t0.x,0.f); bb[1]=fmaxf(t0.y,0.f); bb[2]=fmaxf(t0.z,0.f); bb[3]=fmaxf(t0.w,0.f);
        bb[4]=fmaxf(t1.x,0.f); bb[5]=fmaxf(t1.y,0.f); bb[6]=fmaxf(t1.z,0.f); bb[7]=fmaxf(t1.w,0.f);
    }
    const unsigned short* base = src_tbl + (size_t)b * (LAYER == 1 ? NT : M) * F;

    for (int g = 0; g < 4; ++g) {
        int lr0 = wid * 16 + g * 4;            // local row base of this 4-row group
        size_t eb = ((size_t)row0 + lr0 + i4) * KNB;
        int u;
        if (e < 8) u = idx_k2[eb + e];
        else       u = M + idx_k1[eb + e - 8];
        int dg = deg[b * NT + u];
        float w = rsqrtf((float)(dg < 1 ? 1 : dg));
        float wst = (e >= 8) ? w : 0.f;

        #pragma unroll
        for (int i = 0; i < 4; ++i) {
            floatx2 acc[4];
            if (LAYER == 2) {
                float S = 0.f;
                #pragma unroll
                for (int j = 8; j < 16; ++j) S += __shfl(wst, i * 16 + j);
                #pragma unroll
                for (int j = 0; j < 4; ++j) { acc[j].x = bb[2*j] * S; acc[j].y = bb[2*j+1] * S; }
            } else {
                #pragma unroll
                for (int j = 0; j < 4; ++j) acc[j] = (floatx2){0.f, 0.f};
            }
            #pragma unroll
            for (int c = 0; c < NK / 8; ++c) {
                const unsigned short* sp[8];
                #pragma unroll
                for (int k = 0; k < 8; ++k) {
                    int uk = __shfl(u, i * 16 + c * 8 + k);
                    sp[k] = base + (size_t)uk * F + 8 * lane;
                }
                uint4 v[8];
                if (lane < 36) {
                    #pragma unroll
                    for (int k = 0; k < 8; ++k) v[k] = *(const uint4*)sp[k];
                }
                #pragma unroll
                for (int k = 0; k < 8; ++k) {
                    float wk = __shfl(w, i * 16 + c * 8 + k);
                    floatx2 wk2 = {wk, wk};
                    acc[0] += wk2 * bpair(v[k].x);
                    acc[1] += wk2 * bpair(v[k].y);
                    acc[2] += wk2 * bpair(v[k].z);
                    acc[3] += wk2 * bpair(v[k].w);
                }
            }
            if (lane < 36) {
                uint4 o;
                o.x = (unsigned int)f2b(acc[0].x*0.25f) | ((unsigned int)f2b(acc[0].y*0.25f) << 16);
                o.y = (unsigned int)f2b(acc[1].x*0.25f) | ((unsigned int)f2b(acc[1].y*0.25f) << 16);
                o.z = (unsigned int)f2b(acc[2].x*0.25f) | ((unsigned int)f2b(acc[2].y*0.25f) << 16);
                o.w = (unsigned int)f2b(acc[3].x*0.25f) | ((unsigned int)f2b(acc[3].y*0.25f) << 16);
                *(uint4*)(&sA[(lr0 + i) * F] + 8 * lane) = o;
            }
        }
    }
    __syncthreads();

    // ---- phase B: GEMM sA[64xF] @ Wp + bias; B-frags straight from global (L2) ----
    int wm = wid & 1, wn = wid >> 1;
    int quad = lane >> 4, r16 = lane & 15;
    floatx4 acc[9][2];
    #pragma unroll
    for (int ct = 0; ct < 9; ++ct)
        #pragma unroll
        for (int rt = 0; rt < 2; ++rt)
            acc[ct][rt] = (floatx4){0.f, 0.f, 0.f, 0.f};

    for (int s = 0; s < 9; ++s) {
        short8 a0 = *(const short8*)&sA[(wm * 32 + r16) * F + s * 32 + quad * 8];
        short8 a1 = *(const short8*)&sA[(wm * 32 + 16 + r16) * F + s * 32 + quad * 8];
        const unsigned short* bp = Wp + ((size_t)(s * 4 + quad) * F + wn * 144 + r16) * 8;
        #pragma unroll
        for (int ct = 0; ct < 9; ++ct) {
            short8 bf = *(const short8*)(bp + ct * 128);
            acc[ct][0] = __builtin_amdgcn_mfma_f32_16x16x32_bf16(a0, bf, acc[ct][0], 0, 0, 0);
            acc[ct][1] = __builtin_amdgcn_mfma_f32_16x16x32_bf16(a1, bf, acc[ct][1], 0, 0, 0);
        }
    }

    #pragma unroll
    for (int ct = 0; ct < 9; ++ct) {
        int col = wn * 144 + ct * 16 + r16;
        float bc = bias[col];
        #pragma unroll
        for (int rt = 0; rt < 2; ++rt) {
            #pragma unroll
            for (int rg = 0; rg < 4; ++rg) {
                float v = acc[ct][rt][rg] + bc;
                int grow = row0 + wm * 32 + quad * 4 + rt * 16 + rg;
                if (LAYER == 1)
                    ((unsigned short*)Cout)[(size_t)grow * F + col] = f2b(fmaxf(v, 0.f));
                else
                    ((float*)Cout)[(size_t)grow * F + col] = v;
            }
        }
    }
}

extern "C" void kernel_launch(void* const* d_in, const int* in_sizes, int n_in,
                              void* d_out, int out_size, void* d_ws, size_t ws_size,
                              hipStream_t stream) {
    const float* feat_c = (const float*)d_in[0];
    const float* feat_s = (const float*)d_in[1];
    const int*   idx_k1 = (const int*)d_in[2];
    const int*   idx_k2 = (const int*)d_in[3];
    const float* W1     = (const float*)d_in[4];
    const float* b1     = (const float*)d_in[5];
    const float* W2     = (const float*)d_in[6];
    const float* b2     = (const float*)d_in[7];

    char* ws = (char*)d_ws;
    int*            deg  = (int*)ws;                                    // 256 KB
    unsigned short* Wp1  = (unsigned short*)(ws + 262144);              // 166 KB
    unsigned short* Wp2  = (unsigned short*)(ws + 262144 + 165888);     // 166 KB
    unsigned short* h1b  = (unsigned short*)(ws + 262144 + 2 * 165888); // 18.9 MB (NOT d_out:
                                                                        // fused1 reads featb=d_out)
    unsigned short* featb = (unsigned short*)d_out;  // 37.75 MB bf16 table, dead after fused1
    float*          out   = (float*)d_out;

    hipMemsetAsync(deg, 0, (size_t)B * NT * sizeof(int), stream);
    prep_kernel<<<PREP_CVT + PREP_DEG + PREP_PKW, 256, 0, stream>>>(
        idx_k1, idx_k2, deg, feat_c, feat_s, featb, W1, W2, Wp1, Wp2);

    fused_kernel<1><<<BM / 64, 256, 0, stream>>>(featb, idx_k1, idx_k2, deg, b1, Wp1, b1, (void*)h1b);
    fused_kernel<2><<<BM / 64, 256, 0, stream>>>(h1b,   idx_k1, idx_k2, deg, b1, Wp2, b2, (void*)out);
}